// Round 2
// baseline (504.316 us; speedup 1.0000x reference)
//
#include <hip/hip_runtime.h>
#include <stdint.h>

// ---------------------------------------------------------------------------
// CrossViewAttention on MI355X (gfx950).
//   out_f = softmax(Qf Ks^T)/l / sqrt(512) @ Vf + relu([xf,xs] Wc^T + bc)
//   out_s = softmax(Qs Kf^T)/l / sqrt(512) @ Vs + co_occur
// bf16 MFMA everywhere, fp32 accumulate. B=2, N=4096, D=512.
// ---------------------------------------------------------------------------

using bf16x8 = __attribute__((ext_vector_type(8))) short;   // 8 bf16 = 4 VGPR
using f32x4  = __attribute__((ext_vector_type(4))) float;

typedef __attribute__((address_space(1))) const void as1_void_t;
typedef __attribute__((address_space(3))) void as3_void_t;

__device__ __forceinline__ void gload16(const void* g, void* l) {
  // async global->LDS, 16B per lane; LDS dest = wave-uniform base + lane*16
  __builtin_amdgcn_global_load_lds((as1_void_t*)g, (as3_void_t*)l, 16, 0, 0);
}

__device__ __forceinline__ unsigned f2bf_u(float f) {  // RNE fp32->bf16 bits
  unsigned u = __float_as_uint(f);
  return (u + 0x7fffu + ((u >> 16) & 1u)) >> 16;
}

#define MFMA_BF16(a, b, c) __builtin_amdgcn_mfma_f32_16x16x32_bf16((a), (b), (c), 0, 0, 0)

// ---------------------------------------------------------------------------
// fp32 -> bf16 conversion, 4 elems/thread
__global__ void cvt_bf16(const float* __restrict__ src,
                         unsigned short* __restrict__ dst, int n4) {
  int i = blockIdx.x * blockDim.x + threadIdx.x;
  if (i >= n4) return;
  float4 v = ((const float4*)src)[i];
  uint2 o;
  o.x = f2bf_u(v.x) | (f2bf_u(v.y) << 16);
  o.y = f2bf_u(v.z) | (f2bf_u(v.w) << 16);
  ((uint2*)dst)[i] = o;
}

// Wc [512][1024] -> Wcf [512][512] (cols 0..511), Wcs [512][512] (cols 512..1023)
__global__ void split_wc(const float* __restrict__ Wc,
                         unsigned short* __restrict__ Wf,
                         unsigned short* __restrict__ Ws) {
  int t = blockIdx.x * blockDim.x + threadIdx.x;   // 65536 threads
  int row = t >> 7, col = (t & 127) * 4;
  float4 a = *(const float4*)(Wc + row * 1024 + col);
  float4 b = *(const float4*)(Wc + row * 1024 + 512 + col);
  uint2 oa, ob;
  oa.x = f2bf_u(a.x) | (f2bf_u(a.y) << 16);
  oa.y = f2bf_u(a.z) | (f2bf_u(a.w) << 16);
  ob.x = f2bf_u(b.x) | (f2bf_u(b.y) << 16);
  ob.y = f2bf_u(b.z) | (f2bf_u(b.w) << 16);
  *(uint2*)(Wf + row * 512 + col) = oa;
  *(uint2*)(Ws + row * 512 + col) = ob;
}

// ---------------------------------------------------------------------------
// 128x128-tile GEMM, C = A(row-major [M][512-per-seg]) * W^T (+bias), bf16 MFMA.
// EPI 0: bf16 C [M][512]          (Q, K projections)
// EPI 1: bf16 C transposed to Vt[(src*2+b)*512 + col][4096]   (V projection)
// EPI 2: fp32 relu(C) [M][512], dual A/W segments (co_occur, K=1024)
template<int EPI>
__global__ void __launch_bounds__(256)
gemm_proj(const unsigned short* __restrict__ A1,
          const unsigned short* __restrict__ A2,
          const unsigned short* __restrict__ W1,
          const unsigned short* __restrict__ W2,
          const float* __restrict__ bias,
          void* __restrict__ Cout, int nk) {
  __shared__ __align__(16) unsigned short As[128 * 32];
  __shared__ __align__(16) unsigned short Bs[128 * 32];
  const int tid = threadIdx.x;
  const int w = tid >> 6, lane = tid & 63;
  const int m0 = blockIdx.x * 128, n0 = blockIdx.y * 128;
  const int wm = (w >> 1) * 64, wn = (w & 1) * 64;
  f32x4 acc[4][4] = {};

  for (int ks = 0; ks < nk; ++ks) {
    const unsigned short* Ab = (EPI == 2 && ks >= 16) ? A2 : A1;
    const unsigned short* Wb = (EPI == 2 && ks >= 16) ? W2 : W1;
    const int k0 = (EPI == 2) ? ((ks & 15) * 32) : (ks * 32);
#pragma unroll
    for (int t = 0; t < 2; ++t) {
      const int o = t * 256 + tid;          // 16B chunk ordinal in [128][32] tile
      const int row = o >> 2, seg = o & 3;
      gload16(Ab + (size_t)(m0 + row) * 512 + k0 + seg * 8,
              (char*)As + t * 4096 + w * 1024);
      gload16(Wb + (size_t)(n0 + row) * 512 + k0 + seg * 8,
              (char*)Bs + t * 4096 + w * 1024);
    }
    __syncthreads();
    bf16x8 a[4], b[4];
#pragma unroll
    for (int i = 0; i < 4; ++i) {
      a[i] = *(const bf16x8*)(As + (wm + i * 16 + (lane & 15)) * 32 + (lane >> 4) * 8);
      b[i] = *(const bf16x8*)(Bs + (wn + i * 16 + (lane & 15)) * 32 + (lane >> 4) * 8);
    }
#pragma unroll
    for (int i = 0; i < 4; ++i)
#pragma unroll
      for (int j = 0; j < 4; ++j)
        acc[i][j] = MFMA_BF16(a[i], b[j], acc[i][j]);
    __syncthreads();
  }

  const int lm = lane >> 4, ln = lane & 15;
  if (EPI == 0) {
    unsigned short* Cb = (unsigned short*)Cout;
#pragma unroll
    for (int i = 0; i < 4; ++i)
#pragma unroll
      for (int j = 0; j < 4; ++j) {
        const int col = n0 + wn + j * 16 + ln;
        const float bv = bias[col];
#pragma unroll
        for (int r = 0; r < 4; ++r) {
          const int row = m0 + wm + i * 16 + lm * 4 + r;
          Cb[(size_t)row * 512 + col] = (unsigned short)f2bf_u(acc[i][j][r] + bv);
        }
      }
  } else if (EPI == 1) {
    unsigned short* Cb = (unsigned short*)Cout;
#pragma unroll
    for (int i = 0; i < 4; ++i)
#pragma unroll
      for (int j = 0; j < 4; ++j) {
        const int col = n0 + wn + j * 16 + ln;
        const float bv = bias[col];
#pragma unroll
        for (int r = 0; r < 4; ++r) {
          const int row = m0 + wm + i * 16 + lm * 4 + r;   // [src][b][n] row
          const int sb = row >> 12, n = row & 4095;
          Cb[(size_t)(sb * 512 + col) * 4096 + n] = (unsigned short)f2bf_u(acc[i][j][r] + bv);
        }
      }
  } else {
    float* Cb = (float*)Cout;
#pragma unroll
    for (int i = 0; i < 4; ++i)
#pragma unroll
      for (int j = 0; j < 4; ++j) {
        const int col = n0 + wn + j * 16 + ln;
        const float bv = bias[col];
#pragma unroll
        for (int r = 0; r < 4; ++r) {
          const int row = m0 + wm + i * 16 + lm * 4 + r;
          float v = acc[i][j][r] + bv;
          Cb[(size_t)row * 512 + col] = v > 0.f ? v : 0.f;
        }
      }
  }
}

// ---------------------------------------------------------------------------
// Flash attention: grid (64 q-tiles, B=2, dir=2), 512 thr (8 waves).
// QBLK=64, KVBLK=32. Wave w: QK^T quadrant (qw=w>>1, kw=w&1); PV d-chunk w*64.
// K LDS: [32][512] bf16, XOR-swizzled byte^=((row&7)<<4) via pre-swizzled
// global source (global_load_lds writes linearly). V LDS: [512][32] (from Vt),
// XOR-swizzled byte^=((d&3)<<4).
__global__ void __launch_bounds__(512)
flash_attn(const unsigned short* __restrict__ Qb,
           const unsigned short* __restrict__ Kb,
           const unsigned short* __restrict__ Vt,
           const float* __restrict__ CO,
           float* __restrict__ Out) {
  __shared__ __align__(16) unsigned short Ks[32 * 512];
  __shared__ __align__(16) unsigned short Vs[512 * 32];
  __shared__ __align__(16) float S_lds[64 * 33];           // +1 pad: no conflicts
  __shared__ __align__(16) unsigned short P_lds[64 * 48];  // stride 96B (16B-aligned)
  __shared__ float m_run[64], l_run[64], alpha_l[64];

  const int tid = threadIdx.x;
  const int w = tid >> 6, lane = tid & 63;
  const int q0 = blockIdx.x * 64;
  const int b = blockIdx.y, dir = blockIdx.z;
  const int qw = w >> 1, kw = w & 1;

  const size_t qbase  = (size_t)(dir * 2 + b) * 4096 * 512;
  const size_t kbase  = (size_t)((1 - dir) * 2 + b) * 4096 * 512;
  const size_t vbase  = (size_t)(dir * 2 + b) * 512 * 4096;
  const size_t cobase = (size_t)b * 4096 * 512;
  const size_t obase  = qbase;   // out_f then out_s, same [dir][b][n][d] layout

  if (tid < 64) { m_run[tid] = -1e30f; l_run[tid] = 0.0f; }

  // Hoist Q fragments for this wave's 16 q-rows: 16 k-steps x 8 bf16
  bf16x8 qf[16];
  {
    const int qrow = q0 + qw * 16 + (lane & 15);
#pragma unroll
    for (int g = 0; g < 16; ++g)
      qf[g] = *(const bf16x8*)(Qb + qbase + (size_t)qrow * 512 + g * 32 + (lane >> 4) * 8);
  }

  f32x4 o_acc[4][4] = {};   // [q-subtile][d-subtile], wave owns 64q x 64d
  __syncthreads();

  for (int kt = 0; kt < 128; ++kt) {
    const int kv0 = kt * 32;
    // ---- stage K[32][512] and Vt-slice[512][32], swizzled source ----
#pragma unroll
    for (int t = 0; t < 4; ++t) {
      const int krow = t * 8 + w;                       // one 1KB K-row per wave
      gload16(Kb + kbase + (size_t)(kv0 + krow) * 512 + (lane ^ (krow & 7)) * 8,
              (char*)Ks + krow * 1024);
      const int dbase = (t * 8 + w) * 16;               // 16 Vt rows per wave
      const int d = dbase + (lane >> 2);
      gload16(Vt + vbase + (size_t)d * 4096 + kv0 + (((lane & 3) ^ (d & 3)) * 8),
              (char*)Vs + dbase * 64);
    }
    __syncthreads();

    // ---- QK^T quadrant: S[qw*16..+16][kw*16..+16] ----
    f32x4 s = {};
    {
      const int krow = kw * 16 + (lane & 15);
#pragma unroll
      for (int g = 0; g < 16; ++g) {
        const int chunk = (g * 4 + (lane >> 4)) ^ (krow & 7);
        bf16x8 kf = *(const bf16x8*)((const char*)Ks + krow * 1024 + chunk * 16);
        s = MFMA_BF16(qf[g], kf, s);
      }
      const int col = kw * 16 + (lane & 15);
      const int rb = qw * 16 + (lane >> 4) * 4;
#pragma unroll
      for (int r = 0; r < 4; ++r)
        S_lds[(rb + r) * 33 + col] = s[r];
    }
    __syncthreads();

    // ---- online softmax: wave w owns rows 8w..8w+7, 8 lanes/row ----
    {
      const int row = w * 8 + (lane >> 3);
      const int j = lane & 7;
      const float* Sr = &S_lds[row * 33 + j * 4];
      float v0 = Sr[0], v1 = Sr[1], v2 = Sr[2], v3 = Sr[3];
      float mx = fmaxf(fmaxf(v0, v1), fmaxf(v2, v3));
      mx = fmaxf(mx, __shfl_xor(mx, 1));
      mx = fmaxf(mx, __shfl_xor(mx, 2));
      mx = fmaxf(mx, __shfl_xor(mx, 4));
      const float mold = m_run[row];
      const float mnew = fmaxf(mold, mx);
      float p0 = __expf(v0 - mnew), p1 = __expf(v1 - mnew);
      float p2 = __expf(v2 - mnew), p3 = __expf(v3 - mnew);
      float ls = p0 + p1 + p2 + p3;
      ls += __shfl_xor(ls, 1);
      ls += __shfl_xor(ls, 2);
      ls += __shfl_xor(ls, 4);
      const float alpha = __expf(mold - mnew);
      if (j == 0) {
        m_run[row] = mnew;
        l_run[row] = l_run[row] * alpha + ls;
        alpha_l[row] = alpha;
      }
      uint2 pw;
      pw.x = f2bf_u(p0) | (f2bf_u(p1) << 16);
      pw.y = f2bf_u(p2) | (f2bf_u(p3) << 16);
      *(uint2*)(P_lds + row * 48 + j * 4) = pw;
    }
    __syncthreads();

    // ---- rescale O by alpha, then O += P @ V (wave's 64-wide d-chunk) ----
#pragma unroll
    for (int qi = 0; qi < 4; ++qi) {
      bf16x8 pa = *(const bf16x8*)(P_lds + (qi * 16 + (lane & 15)) * 48 + (lane >> 4) * 8);
#pragma unroll
      for (int r = 0; r < 4; ++r) {
        const float al = alpha_l[qi * 16 + (lane >> 4) * 4 + r];
#pragma unroll
        for (int di = 0; di < 4; ++di)
          o_acc[qi][di][r] *= al;
      }
#pragma unroll
      for (int di = 0; di < 4; ++di) {
        const int d = w * 64 + di * 16 + (lane & 15);
        const int slot = (lane >> 4) ^ (d & 3);
        bf16x8 vf = *(const bf16x8*)((const char*)Vs + d * 64 + slot * 16);
        o_acc[qi][di] = MFMA_BF16(pa, vf, o_acc[qi][di]);
      }
    }
    __syncthreads();
  }

  // ---- epilogue: /l, /sqrt(512), + co_occur ----
  const float rsd = 0.04419417382415922f;   // 1/sqrt(512)
#pragma unroll
  for (int qi = 0; qi < 4; ++qi) {
#pragma unroll
    for (int r = 0; r < 4; ++r) {
      const int ql = qi * 16 + (lane >> 4) * 4 + r;
      const float inv = rsd / l_run[ql];
      const size_t rowoff = (size_t)(q0 + ql) * 512;
#pragma unroll
      for (int di = 0; di < 4; ++di) {
        const int d = w * 64 + di * 16 + (lane & 15);
        Out[obase + rowoff + d] = o_acc[qi][di][r] * inv + CO[cobase + rowoff + d];
      }
    }
  }
}

// ---------------------------------------------------------------------------
extern "C" void kernel_launch(void* const* d_in, const int* in_sizes, int n_in,
                              void* d_out, int out_size, void* d_ws, size_t ws_size,
                              hipStream_t stream) {
  const float* x_f = (const float*)d_in[0];
  const float* x_s = (const float*)d_in[1];
  const float* Wq  = (const float*)d_in[2];
  const float* bq  = (const float*)d_in[3];
  const float* Wk  = (const float*)d_in[4];
  const float* bk  = (const float*)d_in[5];
  const float* Wv  = (const float*)d_in[6];
  const float* bv  = (const float*)d_in[7];
  const float* Wc  = (const float*)d_in[8];
  const float* bc  = (const float*)d_in[9];
  float* out = (float*)d_out;

  // workspace layout (~83 MB total)
  unsigned short* Xb  = (unsigned short*)d_ws;     // [2 src][2 b][4096][512] bf16
  unsigned short* Qb  = Xb + 8388608;
  unsigned short* Kb  = Qb + 8388608;
  unsigned short* Vt  = Kb + 8388608;              // [(src*2+b)*512 + d][4096]
  float*          CO  = (float*)(Vt + 8388608);    // [2 b][4096][512] fp32
  unsigned short* Wqb = (unsigned short*)(CO + 4194304);
  unsigned short* Wkb = Wqb + 262144;
  unsigned short* Wvb = Wkb + 262144;
  unsigned short* Wcf = Wvb + 262144;
  unsigned short* Wcs = Wcf + 262144;

  cvt_bf16<<<4096, 256, 0, stream>>>(x_f, Xb, 1048576);
  cvt_bf16<<<4096, 256, 0, stream>>>(x_s, Xb + 4194304, 1048576);
  cvt_bf16<<<256, 256, 0, stream>>>(Wq, Wqb, 65536);
  cvt_bf16<<<256, 256, 0, stream>>>(Wk, Wkb, 65536);
  cvt_bf16<<<256, 256, 0, stream>>>(Wv, Wvb, 65536);
  split_wc<<<256, 256, 0, stream>>>(Wc, Wcf, Wcs);

  dim3 gQ(128, 4);
  gemm_proj<0><<<gQ, 256, 0, stream>>>(Xb, nullptr, Wqb, nullptr, bq, Qb, 16);
  gemm_proj<0><<<gQ, 256, 0, stream>>>(Xb, nullptr, Wkb, nullptr, bk, Kb, 16);
  gemm_proj<1><<<gQ, 256, 0, stream>>>(Xb, nullptr, Wvb, nullptr, bv, Vt, 16);
  dim3 gC(64, 4);
  gemm_proj<2><<<gC, 256, 0, stream>>>(Xb, Xb + 4194304, Wcf, Wcs, bc, CO, 32);

  dim3 gF(64, 2, 2);
  flash_attn<<<gF, 512, 0, stream>>>(Qb, Kb, Vt, CO, out);
}

// Round 3
// 490.188 us; speedup vs baseline: 1.0288x; 1.0288x over previous
//
#include <hip/hip_runtime.h>
#include <stdint.h>

// ---------------------------------------------------------------------------
// CrossViewAttention on MI355X (gfx950).
//   out_f = softmax(Qf Ks^T)/l / sqrt(512) @ Vf + relu([xf,xs] Wc^T + bc)
//   out_s = softmax(Qs Kf^T)/l / sqrt(512) @ Vs + co_occur
// bf16 MFMA, fp32 accumulate. B=2, N=4096, D=512.
// R2: raw-barrier pipelines (T3/T4): double-buffered LDS + counted prefetch
// spanning one full iteration; 3 barriers/iter in flash, 1/K-step in GEMM.
// ---------------------------------------------------------------------------

using bf16x8 = __attribute__((ext_vector_type(8))) short;   // 8 bf16 = 4 VGPR
using f32x4  = __attribute__((ext_vector_type(4))) float;

typedef __attribute__((address_space(1))) const void as1_void_t;
typedef __attribute__((address_space(3))) void as3_void_t;

__device__ __forceinline__ void gload16(const void* g, void* l) {
  // async global->LDS, 16B per lane; LDS dest = wave-uniform base + lane*16
  __builtin_amdgcn_global_load_lds((as1_void_t*)g, (as3_void_t*)l, 16, 0, 0);
}

// raw barrier with explicit waits (rule #18: asm wait + sched_barrier fence)
#define BAR_VM0()                                                  \
  do {                                                             \
    asm volatile("s_waitcnt vmcnt(0) lgkmcnt(0)" ::: "memory");    \
    __builtin_amdgcn_s_barrier();                                  \
    __builtin_amdgcn_sched_barrier(0);                             \
  } while (0)

#define BAR_LGKM()                                                 \
  do {                                                             \
    asm volatile("s_waitcnt lgkmcnt(0)" ::: "memory");             \
    __builtin_amdgcn_s_barrier();                                  \
    __builtin_amdgcn_sched_barrier(0);                             \
  } while (0)

__device__ __forceinline__ unsigned f2bf_u(float f) {  // RNE fp32->bf16 bits
  unsigned u = __float_as_uint(f);
  return (u + 0x7fffu + ((u >> 16) & 1u)) >> 16;
}

#define MFMA_BF16(a, b, c) __builtin_amdgcn_mfma_f32_16x16x32_bf16((a), (b), (c), 0, 0, 0)

// ---------------------------------------------------------------------------
// fp32 -> bf16 conversion, 4 elems/thread
__global__ void cvt_bf16(const float* __restrict__ src,
                         unsigned short* __restrict__ dst, int n4) {
  int i = blockIdx.x * blockDim.x + threadIdx.x;
  if (i >= n4) return;
  float4 v = ((const float4*)src)[i];
  uint2 o;
  o.x = f2bf_u(v.x) | (f2bf_u(v.y) << 16);
  o.y = f2bf_u(v.z) | (f2bf_u(v.w) << 16);
  ((uint2*)dst)[i] = o;
}

// Wc [512][1024] -> Wcf [512][512] (cols 0..511), Wcs [512][512] (cols 512..1023)
__global__ void split_wc(const float* __restrict__ Wc,
                         unsigned short* __restrict__ Wf,
                         unsigned short* __restrict__ Ws) {
  int t = blockIdx.x * blockDim.x + threadIdx.x;   // 65536 threads
  int row = t >> 7, col = (t & 127) * 4;
  float4 a = *(const float4*)(Wc + row * 1024 + col);
  float4 b = *(const float4*)(Wc + row * 1024 + 512 + col);
  uint2 oa, ob;
  oa.x = f2bf_u(a.x) | (f2bf_u(a.y) << 16);
  oa.y = f2bf_u(a.z) | (f2bf_u(a.w) << 16);
  ob.x = f2bf_u(b.x) | (f2bf_u(b.y) << 16);
  ob.y = f2bf_u(b.z) | (f2bf_u(b.w) << 16);
  *(uint2*)(Wf + row * 512 + col) = oa;
  *(uint2*)(Ws + row * 512 + col) = ob;
}

// ---------------------------------------------------------------------------
// 128x128-tile GEMM, C = A(row-major) * W^T (+bias), bf16 MFMA, double-buffered
// LDS with prefetch spanning one K-step (1 raw barrier per K-step).
// EPI 0: bf16 C [M][512]          (Q, K projections)
// EPI 1: bf16 C transposed to Vt[(src*2+b)*512 + col][4096]   (V projection)
// EPI 2: fp32 relu(C) [M][512], dual A/W segments (co_occur, K=1024)
template<int EPI>
__global__ void __launch_bounds__(256)
gemm_proj(const unsigned short* __restrict__ A1,
          const unsigned short* __restrict__ A2,
          const unsigned short* __restrict__ W1,
          const unsigned short* __restrict__ W2,
          const float* __restrict__ bias,
          void* __restrict__ Cout, int nk) {
  __shared__ __align__(16) unsigned short As[2][128 * 32];
  __shared__ __align__(16) unsigned short Bs[2][128 * 32];
  const int tid = threadIdx.x;
  const int w = tid >> 6, lane = tid & 63;
  const int m0 = blockIdx.x * 128, n0 = blockIdx.y * 128;
  const int wm = (w >> 1) * 64, wn = (w & 1) * 64;
  f32x4 acc[4][4] = {};

  auto stage = [&](int ks, int bi) {
    const unsigned short* Ab = (EPI == 2 && ks >= 16) ? A2 : A1;
    const unsigned short* Wb = (EPI == 2 && ks >= 16) ? W2 : W1;
    const int k0 = (EPI == 2) ? ((ks & 15) * 32) : (ks * 32);
#pragma unroll
    for (int t = 0; t < 2; ++t) {
      const int o = t * 256 + tid;          // 16B chunk ordinal in [128][32] tile
      const int row = o >> 2, seg = o & 3;
      gload16(Ab + (size_t)(m0 + row) * 512 + k0 + seg * 8,
              (char*)As[bi] + t * 4096 + w * 1024);
      gload16(Wb + (size_t)(n0 + row) * 512 + k0 + seg * 8,
              (char*)Bs[bi] + t * 4096 + w * 1024);
    }
  };

  stage(0, 0);
  for (int ks = 0; ks < nk; ++ks) {
    const int bi = ks & 1;
    // tile ks resident in buf bi; all waves done reading buf bi^1 (prev iter)
    BAR_VM0();
    if (ks + 1 < nk) stage(ks + 1, bi ^ 1);   // prefetch spans the MFMA phase
    bf16x8 a[4], b[4];
#pragma unroll
    for (int i = 0; i < 4; ++i) {
      a[i] = *(const bf16x8*)(As[bi] + (wm + i * 16 + (lane & 15)) * 32 + (lane >> 4) * 8);
      b[i] = *(const bf16x8*)(Bs[bi] + (wn + i * 16 + (lane & 15)) * 32 + (lane >> 4) * 8);
    }
#pragma unroll
    for (int i = 0; i < 4; ++i)
#pragma unroll
      for (int j = 0; j < 4; ++j)
        acc[i][j] = MFMA_BF16(a[i], b[j], acc[i][j]);
  }

  const int lm = lane >> 4, ln = lane & 15;
  if (EPI == 0) {
    unsigned short* Cb = (unsigned short*)Cout;
#pragma unroll
    for (int i = 0; i < 4; ++i)
#pragma unroll
      for (int j = 0; j < 4; ++j) {
        const int col = n0 + wn + j * 16 + ln;
        const float bv = bias[col];
#pragma unroll
        for (int r = 0; r < 4; ++r) {
          const int row = m0 + wm + i * 16 + lm * 4 + r;
          Cb[(size_t)row * 512 + col] = (unsigned short)f2bf_u(acc[i][j][r] + bv);
        }
      }
  } else if (EPI == 1) {
    unsigned short* Cb = (unsigned short*)Cout;
#pragma unroll
    for (int i = 0; i < 4; ++i)
#pragma unroll
      for (int j = 0; j < 4; ++j) {
        const int col = n0 + wn + j * 16 + ln;
        const float bv = bias[col];
#pragma unroll
        for (int r = 0; r < 4; ++r) {
          const int row = m0 + wm + i * 16 + lm * 4 + r;   // [src][b][n] row
          const int sb = row >> 12, n = row & 4095;
          Cb[(size_t)(sb * 512 + col) * 4096 + n] = (unsigned short)f2bf_u(acc[i][j][r] + bv);
        }
      }
  } else {
    float* Cb = (float*)Cout;
#pragma unroll
    for (int i = 0; i < 4; ++i)
#pragma unroll
      for (int j = 0; j < 4; ++j) {
        const int col = n0 + wn + j * 16 + ln;
        const float bv = bias[col];
#pragma unroll
        for (int r = 0; r < 4; ++r) {
          const int row = m0 + wm + i * 16 + lm * 4 + r;
          float v = acc[i][j][r] + bv;
          Cb[(size_t)row * 512 + col] = v > 0.f ? v : 0.f;
        }
      }
  }
}

// ---------------------------------------------------------------------------
// Flash attention: grid (64 q-tiles, B=2, dir=2), 512 thr (8 waves).
// QBLK=64, KVBLK=32. Wave w: QK^T quadrant (qw=w>>1, kw=w&1); PV d-chunk w*64.
// Double-buffered K/V (143 KB LDS); prefetch of tile kt+1 issued right after
// the tile-kt-ready barrier, waited one iteration later. 3 raw barriers/iter:
//   (1) vmcnt(0)+bar  : tile kt in LDS + all waves done with kt-1 LDS reads
//   (2) lgkm+bar      : S_lds handoff (QK -> softmax)
//   (3) lgkm+bar      : P_lds/alpha handoff (softmax -> PV)
// K LDS: [32][512] bf16 XOR-swizzled chunk^=(row&7); V LDS: [512][32]
// slot^=(d&3) — both via pre-swizzled global source (linear gload_lds dest).
__global__ void __launch_bounds__(512)
flash_attn(const unsigned short* __restrict__ Qb,
           const unsigned short* __restrict__ Kb,
           const unsigned short* __restrict__ Vt,
           const float* __restrict__ CO,
           float* __restrict__ Out) {
  __shared__ __align__(16) unsigned short Ks[2][32 * 512];
  __shared__ __align__(16) unsigned short Vs[2][512 * 32];
  __shared__ __align__(16) float S_lds[64 * 36];           // stride 36: b128 reads conflict-free
  __shared__ __align__(16) unsigned short P_lds[64 * 48];  // stride 96B: b128 reads conflict-free
  __shared__ __align__(16) float m_run[64];
  __shared__ __align__(16) float l_run[64];
  __shared__ __align__(16) float alpha_l[64];

  const int tid = threadIdx.x;
  const int w = tid >> 6, lane = tid & 63;
  const int q0 = blockIdx.x * 64;
  const int b = blockIdx.y, dir = blockIdx.z;
  const int qw = w >> 1, kw = w & 1;

  const size_t qbase  = (size_t)(dir * 2 + b) * 4096 * 512;
  const size_t kbase  = (size_t)((1 - dir) * 2 + b) * 4096 * 512;
  const size_t vbase  = (size_t)(dir * 2 + b) * 512 * 4096;
  const size_t cobase = (size_t)b * 4096 * 512;
  const size_t obase  = qbase;   // out_f then out_s, same [dir][b][n][d] layout

  auto stage_tiles = [&](int kt, int bi) {
    const int kv0 = kt * 32;
#pragma unroll
    for (int t = 0; t < 4; ++t) {
      const int krow = t * 8 + w;                       // one 1KB K-row per wave
      gload16(Kb + kbase + (size_t)(kv0 + krow) * 512 + (lane ^ (krow & 7)) * 8,
              (char*)Ks[bi] + krow * 1024);
      const int dbase = (t * 8 + w) * 16;               // 16 Vt rows per wave
      const int d = dbase + (lane >> 2);
      gload16(Vt + vbase + (size_t)d * 4096 + kv0 + (((lane & 3) ^ (d & 3)) * 8),
              (char*)Vs[bi] + dbase * 64);
    }
  };

  if (tid < 64) { m_run[tid] = -1e30f; l_run[tid] = 0.0f; }

  stage_tiles(0, 0);                       // tile 0 in flight during Q hoist

  // Hoist Q fragments for this wave's 16 q-rows: 16 k-steps x 8 bf16
  bf16x8 qf[16];
  {
    const int qrow = q0 + qw * 16 + (lane & 15);
#pragma unroll
    for (int g = 0; g < 16; ++g)
      qf[g] = *(const bf16x8*)(Qb + qbase + (size_t)qrow * 512 + g * 32 + (lane >> 4) * 8);
  }

  f32x4 o_acc[4][4] = {};   // [q-subtile][d-subtile], wave owns 64q x 64d

  for (int kt = 0; kt < 128; ++kt) {
    const int bi = kt & 1;
    const unsigned short* Kc = Ks[bi];
    const unsigned short* Vc = Vs[bi];

    // (1) tile kt resident; all waves finished iter kt-1's LDS reads
    BAR_VM0();
    if (kt < 127) stage_tiles(kt + 1, bi ^ 1);   // prefetch spans whole iter

    // ---- QK^T quadrant: S[qw*16..+16][kw*16..+16], 2 MFMA chains ----
    {
      const int krow = kw * 16 + (lane & 15);
      f32x4 s0 = {}, s1 = {};
#pragma unroll
      for (int g = 0; g < 8; ++g) {
        const int c0 = (g * 4 + (lane >> 4)) ^ (krow & 7);
        const int c1 = ((g + 8) * 4 + (lane >> 4)) ^ (krow & 7);
        bf16x8 k0 = *(const bf16x8*)((const char*)Kc + krow * 1024 + c0 * 16);
        bf16x8 k1 = *(const bf16x8*)((const char*)Kc + krow * 1024 + c1 * 16);
        s0 = MFMA_BF16(qf[g], k0, s0);
        s1 = MFMA_BF16(qf[g + 8], k1, s1);
      }
      const int col = kw * 16 + (lane & 15);
      const int rb = qw * 16 + (lane >> 4) * 4;
#pragma unroll
      for (int r = 0; r < 4; ++r)
        S_lds[(rb + r) * 36 + col] = s0[r] + s1[r];
    }
    // (2) S handoff
    BAR_LGKM();

    // ---- online softmax: wave w owns rows 8w..8w+7, 8 lanes/row ----
    {
      const int row = w * 8 + (lane >> 3);
      const int j = lane & 7;
      f32x4 sv = *(const f32x4*)&S_lds[row * 36 + j * 4];
      float mx = fmaxf(fmaxf(sv[0], sv[1]), fmaxf(sv[2], sv[3]));
      mx = fmaxf(mx, __shfl_xor(mx, 1));
      mx = fmaxf(mx, __shfl_xor(mx, 2));
      mx = fmaxf(mx, __shfl_xor(mx, 4));
      const float mold = m_run[row];
      const float mnew = fmaxf(mold, mx);
      float p0 = __expf(sv[0] - mnew), p1 = __expf(sv[1] - mnew);
      float p2 = __expf(sv[2] - mnew), p3 = __expf(sv[3] - mnew);
      float ls = p0 + p1 + p2 + p3;
      ls += __shfl_xor(ls, 1);
      ls += __shfl_xor(ls, 2);
      ls += __shfl_xor(ls, 4);
      const float alpha = __expf(mold - mnew);
      if (j == 0) {
        m_run[row] = mnew;
        l_run[row] = l_run[row] * alpha + ls;
        alpha_l[row] = alpha;
      }
      uint2 pw;
      pw.x = f2bf_u(p0) | (f2bf_u(p1) << 16);
      pw.y = f2bf_u(p2) | (f2bf_u(p3) << 16);
      *(uint2*)(P_lds + row * 48 + j * 4) = pw;
    }
    // (3) P/alpha handoff
    BAR_LGKM();

    // ---- rescale O by alpha, then O += P @ V (wave's 64-wide d-chunk) ----
#pragma unroll
    for (int qi = 0; qi < 4; ++qi) {
      bf16x8 pa = *(const bf16x8*)(P_lds + (qi * 16 + (lane & 15)) * 48 + (lane >> 4) * 8);
      f32x4 al4 = *(const f32x4*)&alpha_l[qi * 16 + (lane >> 4) * 4];
#pragma unroll
      for (int di = 0; di < 4; ++di)
        o_acc[qi][di] *= al4;
#pragma unroll
      for (int di = 0; di < 4; ++di) {
        const int d = w * 64 + di * 16 + (lane & 15);
        const int slot = (lane >> 4) ^ (d & 3);
        bf16x8 vf = *(const bf16x8*)((const char*)Vc + d * 64 + slot * 16);
        o_acc[qi][di] = MFMA_BF16(pa, vf, o_acc[qi][di]);
      }
    }
    // loop back: barrier (1) of kt+1 doubles as end-of-iter WAR barrier
  }

  // final l_run values must be visible to all waves
  BAR_LGKM();

  // ---- epilogue: /l, /sqrt(512), + co_occur ----
  const float rsd = 0.04419417382415922f;   // 1/sqrt(512)
#pragma unroll
  for (int qi = 0; qi < 4; ++qi) {
#pragma unroll
    for (int r = 0; r < 4; ++r) {
      const int ql = qi * 16 + (lane >> 4) * 4 + r;
      const float inv = rsd / l_run[ql];
      const size_t rowoff = (size_t)(q0 + ql) * 512;
#pragma unroll
      for (int di = 0; di < 4; ++di) {
        const int d = w * 64 + di * 16 + (lane & 15);
        Out[obase + rowoff + d] = o_acc[qi][di][r] * inv + CO[cobase + rowoff + d];
      }
    }
  }
}

// ---------------------------------------------------------------------------
extern "C" void kernel_launch(void* const* d_in, const int* in_sizes, int n_in,
                              void* d_out, int out_size, void* d_ws, size_t ws_size,
                              hipStream_t stream) {
  const float* x_f = (const float*)d_in[0];
  const float* x_s = (const float*)d_in[1];
  const float* Wq  = (const float*)d_in[2];
  const float* bq  = (const float*)d_in[3];
  const float* Wk  = (const float*)d_in[4];
  const float* bk  = (const float*)d_in[5];
  const float* Wv  = (const float*)d_in[6];
  const float* bv  = (const float*)d_in[7];
  const float* Wc  = (const float*)d_in[8];
  const float* bc  = (const float*)d_in[9];
  float* out = (float*)d_out;

  // workspace layout (~83 MB total)
  unsigned short* Xb  = (unsigned short*)d_ws;     // [2 src][2 b][4096][512] bf16
  unsigned short* Qb  = Xb + 8388608;
  unsigned short* Kb  = Qb + 8388608;
  unsigned short* Vt  = Kb + 8388608;              // [(src*2+b)*512 + d][4096]
  float*          CO  = (float*)(Vt + 8388608);    // [2 b][4096][512] fp32
  unsigned short* Wqb = (unsigned short*)(CO + 4194304);
  unsigned short* Wkb = Wqb + 262144;
  unsigned short* Wvb = Wkb + 262144;
  unsigned short* Wcf = Wvb + 262144;
  unsigned short* Wcs = Wcf + 262144;

  cvt_bf16<<<4096, 256, 0, stream>>>(x_f, Xb, 1048576);
  cvt_bf16<<<4096, 256, 0, stream>>>(x_s, Xb + 4194304, 1048576);
  cvt_bf16<<<256, 256, 0, stream>>>(Wq, Wqb, 65536);
  cvt_bf16<<<256, 256, 0, stream>>>(Wk, Wkb, 65536);
  cvt_bf16<<<256, 256, 0, stream>>>(Wv, Wvb, 65536);
  split_wc<<<256, 256, 0, stream>>>(Wc, Wcf, Wcs);

  dim3 gQ(128, 4);
  gemm_proj<0><<<gQ, 256, 0, stream>>>(Xb, nullptr, Wqb, nullptr, bq, Qb, 16);
  gemm_proj<0><<<gQ, 256, 0, stream>>>(Xb, nullptr, Wkb, nullptr, bk, Kb, 16);
  gemm_proj<1><<<gQ, 256, 0, stream>>>(Xb, nullptr, Wvb, nullptr, bv, Vt, 16);
  dim3 gC(64, 4);
  gemm_proj<2><<<gC, 256, 0, stream>>>(Xb, Xb + 4194304, Wcf, Wcs, bc, CO, 32);

  dim3 gF(64, 2, 2);
  flash_attn<<<gF, 512, 0, stream>>>(Qb, Kb, Vt, CO, out);
}